// Round 1
// baseline (678.429 us; speedup 1.0000x reference)
//
#include <hip/hip_runtime.h>

// Readout: per-graph softmax-weighted segment sum.
// out[g,f] = sum_{i in g} x[i,f]*exp(x[i,f]) / sum_{i in g} exp(x[i,f])
// node_graph_indices is SORTED -> each graph is a contiguous row range.
// One wave (64 lanes) per graph: binary-search the range, stream it with
// float4 loads (lane = r*16+q covers 4 rows x 16 float4 = 1024B/iter,
// fully coalesced), accumulate num/den in registers, shfl-reduce, write.

__device__ __forceinline__ int lower_bound_i32(const int* __restrict__ idx,
                                               int n, int target) {
    int lo = 0, hi = n;
    while (lo < hi) {
        int mid = (lo + hi) >> 1;
        if (idx[mid] < target) lo = mid + 1;
        else hi = mid;
    }
    return lo;
}

__global__ __launch_bounds__(256) void readout_kernel(
    const float* __restrict__ x,      // (n_atoms, 64)
    const int* __restrict__ gidx,     // (n_atoms,) sorted
    float* __restrict__ out,          // (num_graphs, 64)
    int n_atoms, int num_graphs)
{
    const int wave = threadIdx.x >> 6;          // 4 waves / block
    const int g = blockIdx.x * 4 + wave;        // one graph per wave
    if (g >= num_graphs) return;

    const int lane = threadIdx.x & 63;
    const int r = lane >> 4;                    // row-in-group 0..3
    const int q = lane & 15;                    // float4 quad 0..15 (feature q*4..q*4+3)

    // Contiguous atom range of graph g (wave-uniform redundant search).
    const int start = lower_bound_i32(gidx, n_atoms, g);
    const int end   = lower_bound_i32(gidx, n_atoms, g + 1);

    const float4* __restrict__ xq = (const float4*)x;  // row a -> xq[a*16 + q]

    float4 num = make_float4(0.f, 0.f, 0.f, 0.f);
    float4 den = make_float4(0.f, 0.f, 0.f, 0.f);

    for (int a = start + r; a < end; a += 4) {
        float4 v = xq[(size_t)a * 16 + q];
        float4 e;
        e.x = __expf(v.x);
        e.y = __expf(v.y);
        e.z = __expf(v.z);
        e.w = __expf(v.w);
        den.x += e.x;          den.y += e.y;
        den.z += e.z;          den.w += e.w;
        num.x += v.x * e.x;    num.y += v.y * e.y;
        num.z += v.z * e.z;    num.w += v.w * e.w;
    }

    // Reduce across the 4 row-groups (lanes differing in bits 4 and 5).
    #pragma unroll
    for (int off = 16; off <= 32; off <<= 1) {
        num.x += __shfl_xor(num.x, off);
        num.y += __shfl_xor(num.y, off);
        num.z += __shfl_xor(num.z, off);
        num.w += __shfl_xor(num.w, off);
        den.x += __shfl_xor(den.x, off);
        den.y += __shfl_xor(den.y, off);
        den.z += __shfl_xor(den.z, off);
        den.w += __shfl_xor(den.w, off);
    }

    if (r == 0) {
        float4 o;
        o.x = (den.x != 0.f) ? num.x / den.x : 0.f;
        o.y = (den.y != 0.f) ? num.y / den.y : 0.f;
        o.z = (den.z != 0.f) ? num.z / den.z : 0.f;
        o.w = (den.w != 0.f) ? num.w / den.w : 0.f;
        ((float4*)out)[(size_t)g * 16 + q] = o;   // 16 lanes x 16B = 256B row
    }
}

extern "C" void kernel_launch(void* const* d_in, const int* in_sizes, int n_in,
                              void* d_out, int out_size, void* d_ws, size_t ws_size,
                              hipStream_t stream) {
    const float* x    = (const float*)d_in[0];
    const int*   gidx = (const int*)d_in[1];
    float*       out  = (float*)d_out;

    const int n_atoms    = in_sizes[1];       // 2,000,000
    const int num_graphs = out_size / 64;     // 16384 (F = 64)

    const int blocks = (num_graphs + 3) / 4;  // 4 graphs (waves) per block
    readout_kernel<<<blocks, 256, 0, stream>>>(x, gidx, out, n_atoms, num_graphs);
}